// Round 7
// baseline (384.910 us; speedup 1.0000x reference)
//
#include <hip/hip_runtime.h>

#define EPSF 1e-8f

constexpr int NB = 64;   // batch
constexpr int NO = 64;   // out capsules
constexpr int NI = 1152; // in capsules
constexpr int ND = 16;   // pose dims

constexpr int RSTRIDE = 260;            // 256 floats + 4 pad (16B-aligned rows)
constexpr int BUFSZ   = 64 * RSTRIDE;   // one W-tile: 64 o-rows (66,560 B)

typedef float v2f __attribute__((ext_vector_type(2)));
typedef float v4f __attribute__((ext_vector_type(4)));

// fp32 row loader ------------------------------------------------------------
__device__ __forceinline__ void loadrow16f(const float* __restrict__ base,
                                           size_t elem, float* f){
  const float4* p = (const float4*)(base + elem);
  float4 x0=p[0], x1=p[1], x2=p[2], x3=p[3];
  f[0]=x0.x; f[1]=x0.y; f[2]=x0.z; f[3]=x0.w;
  f[4]=x1.x; f[5]=x1.y; f[6]=x1.z; f[7]=x1.w;
  f[8]=x2.x; f[9]=x2.y; f[10]=x2.z; f[11]=x2.w;
  f[12]=x3.x; f[13]=x3.y; f[14]=x3.z; f[15]=x3.w;
}

// async global->LDS, 16 B per lane; lds dst is wave-uniform base + lane*16
__device__ __forceinline__ void gl_lds16(const float* g, float* l){
  __builtin_amdgcn_global_load_lds(
      (const __attribute__((address_space(1))) unsigned int*)g,
      (__attribute__((address_space(3))) unsigned int*)l,
      16, 0, 0);
}

// ---------------- heavy kernel --------------------------------------------
// 2-blocks/CU inter-block overlap, sized so placement is guaranteed:
// NW=4 (256-thr) blocks, single 66,560 B tile -> 2 blocks/CU = 8 waves/CU =
// 2 waves/SIMD @128 VGPR (256 of 512 regs) -- the exact per-SIMD loading R0
// ran at 1x8-wave block. (R6 measured that 4 waves/SIMD @128 VGPR does NOT
// place: occupancy stayed 21% -> 128-VGPR waves cap at 2/SIMD. Inter-block
// overlap only needs 2 independent barrier domains, not more waves.)
// While block A drains its stage-DMA barrier, block B computes.
// grid = (NB/8)*CH = 512 blocks, ALL co-resident -> same-c blocks share their
// XCD's L2 W-slice concurrently (R6's 2-round serial execution doubled FETCH;
// this restores temporal sharing).
// Loop = 2 barriers/column: sync(reads done) -> stage -> u-load (overlaps own
// DMA) -> sync(drain) -> compute. No mid-compute barrier -> no liveness spill.
// __launch_bounds__ 2nd arg calibrated: (512,2)->128 VGPR, (512,4)->64+spill;
// 16/NW targets the 128-VGPR cap for every NW. 1024-thr blocks failed to
// launch (R3/R4) -- do not reintroduce.
template<int NW, bool ESTEP>
__global__ __launch_bounds__(NW*64, 16/NW) void k_heavy(
    const float* __restrict__ u, const float* __restrict__ W,
    const float* __restrict__ bias,
    const float* __restrict__ mean0, const float* __restrict__ i2v0,
    const float* __restrict__ c0,
    float* __restrict__ S1p, float* __restrict__ S2p, float* __restrict__ Wsp,
    const int CH)
{
  const int CI = NI / CH;
  constexpr int ROWS = 64 / NW;
  const int bid = blockIdx.x;
  const int bg = bid / CH, c = bid % CH;
  const int t = threadIdx.x, lane = t & 63, w = t >> 6;
  const int b0 = bg*(2*NW) + 2*w, b1 = b0 + 1;
  const int i0 = c*CI;

  __shared__ float buf[BUFSZ];   // 66,560 B -> 2 blocks/CU

  // per-lane (=o) constants
  float bs[16]; loadrow16f(bias, (size_t)lane*ND, bs);
  v2f mr[16], ir[16]; v2f c01 = {0.f, 0.f};
  if (ESTEP){
    const size_t m0 = ((size_t)b0*NO + lane)*ND;
    const size_t m1 = ((size_t)b1*NO + lane)*ND;
    #pragma unroll
    for (int e=0;e<16;++e){
      mr[e] = v2f{mean0[m0+e], mean0[m1+e]};
      ir[e] = v2f{i2v0[m0+e], i2v0[m1+e]};
    }
    c01 = v2f{c0[(size_t)b0*NO + lane], c0[(size_t)b1*NO + lane]};
  }

  v2f S1[16], S2[16]; v2f wsum = {0.f, 0.f};
  #pragma unroll
  for (int e=0;e<16;++e){ S1[e]=v2f{0.f,0.f}; S2[e]=v2f{0.f,0.f}; }

  // stage W tile for column i: wave w covers ROWS o-rows, one gl_lds16 per
  // row (64 lanes x 16 B = full 1 KB row, linear dst)
  auto stage = [&](int i){
    const float* gbase = W + (size_t)i*256 + (size_t)lane*4;
    #pragma unroll
    for (int r=0;r<ROWS;++r){
      const int o = w*ROWS + r;
      gl_lds16(gbase + (size_t)o*NI*256, buf + o*RSTRIDE);
    }
  };

  const float* row = &buf[lane*RSTRIDE];

  for (int ii=0; ii<CI; ++ii){
    const int i = i0 + ii;
    __syncthreads();                 // prior column's buf reads complete
    stage(i);                        // async DMA into buf

    // u rows for both batches (global, independent of buf -> overlaps DMA)
    v2f u01[16];
    {
      const float4* pa = (const float4*)(u + ((size_t)b0*NI + i)*ND);
      const float4* pb = (const float4*)(u + ((size_t)b1*NI + i)*ND);
      #pragma unroll
      for (int q=0;q<4;++q){
        float4 xa = pa[q], xb = pb[q];
        u01[q*4+0] = v2f{xa.x, xb.x};
        u01[q*4+1] = v2f{xa.y, xb.y};
        u01[q*4+2] = v2f{xa.z, xb.z};
        u01[q*4+3] = v2f{xa.w, xb.w};
      }
    }
    v2f ss = {0.f, 0.f};
    #pragma unroll
    for (int d=0;d<16;++d){ v2f x = u01[d] + EPSF; ss += x*x; }
    const v2f av = {sqrtf(ss.x), sqrtf(ss.y)};

    __syncthreads();                 // stage DMA drained (vmcnt0 + barrier)

    // V for this lane's o, both batches packed (wide LDS reads)
    v2f V[16];
    #pragma unroll
    for (int e=0;e<16;++e){ float b = bs[e] + EPSF; V[e] = v2f{b, b}; }
    #pragma unroll
    for (int e=0;e<16;++e){
      #pragma unroll
      for (int dq=0; dq<4; ++dq){
        const float4 wv = *(const float4*)(row + e*16 + dq*4);
        const int d = dq*4;
        V[e] += wv.x*u01[d+0];
        V[e] += wv.y*u01[d+1];
        V[e] += wv.z*u01[d+2];
        V[e] += wv.w*u01[d+3];
      }
    }

    v2f wg;
    if (ESTEP){
      v2f la = {0.f, 0.f};
      #pragma unroll
      for (int e=0;e<16;++e){ v2f df = V[e]-mr[e]; la += df*df*ir[e]; }
      v2f ap = c01 * v2f{__expf(-la.x), __expf(-la.y)};
      float q0 = ap.x, q1 = ap.y;
      #pragma unroll
      for (int off=32; off; off>>=1){
        q0 += __shfl_xor(q0, off);
        q1 += __shfl_xor(q1, off);
      }
      wg = v2f{ap.x/(q0 + EPSF)*av.x, ap.y/(q1 + EPSF)*av.y};
    } else {
      wg = av;                      // uniform rr: 1/64 applied in k_mred
    }
    wsum += wg;
    #pragma unroll
    for (int e=0;e<16;++e){
      v2f tv = wg*V[e]; S1[e]+=tv; S2[e]+=tv*V[e];
    }
  }

  // store partials: each wave owns distinct b -> no cross-wave reduction
  const size_t ba = (((size_t)b0*CH + c)*NO + lane);
  const size_t bb = (((size_t)b1*CH + c)*NO + lane);
  #pragma unroll
  for (int e=0;e<16;++e){
    S1p[ba*ND+e]=S1[e].x; S2p[ba*ND+e]=S2[e].x;
    S1p[bb*ND+e]=S1[e].y; S2p[bb*ND+e]=S2[e].y;
  }
  Wsp[ba] = wsum.x; Wsp[bb] = wsum.y;  // m-pass: sum a_i; e-pass: sum rr*a
}

// ---------------- reduce m-step partials -> mean0,i2v0,c0 -------------------
// Wave-parallel: all 64 lanes load; lane = (c-group cg = t>>2) x (e-quad
// q = t&3); float4-over-e loads; serial depth CH/16; butterfly shfl_xor
// combines; epilogue distributed (no t==0 loops). (R5: tail 152 -> 69 us.)
__global__ __launch_bounds__(64) void k_mred(
    const float* __restrict__ beta_a, const float* __restrict__ beta_u,
    const float* __restrict__ S1p, const float* __restrict__ S2p,
    const float* __restrict__ Wsp, const int CH,
    float* __restrict__ mean0, float* __restrict__ i2v0, float* __restrict__ c0)
{
  const int bo = blockIdx.x;
  const int b = bo >> 6, o = bo & 63;
  const int t = threadIdx.x;
  const int q = t & 3, cg = t >> 2;

  v4f s1 = {0.f,0.f,0.f,0.f}, s2 = {0.f,0.f,0.f,0.f};
  for (int c = cg; c < CH; c += 16){
    const size_t base = ((((size_t)b*CH)+c)*NO + o)*ND + 4*q;
    s1 += *(const v4f*)(S1p + base);
    s2 += *(const v4f*)(S2p + base);
  }
  #pragma unroll
  for (int off=4; off<64; off<<=1){
    #pragma unroll
    for (int k=0;k<4;++k){
      s1[k] += __shfl_xor(s1[k], off);
      s2[k] += __shfl_xor(s2[k], off);
    }
  }
  float wv = 0.f;
  for (int c = t; c < CH; c += 64)
    wv += Wsp[(((size_t)b*CH)+c)*NO + o];
  #pragma unroll
  for (int off=1; off<64; off<<=1) wv += __shfl_xor(wv, off);

  const float rrsum = wv * (1.f/64.f);
  const float inv = 1.f/(rrsum + EPSF);
  const float bu = beta_u[o];
  v4f T1 = s1*(1.f/64.f), T2 = s2*(1.f/64.f);
  v4f m   = T1*inv;
  v4f var = (T2 - 2.f*m*T1 + m*m*rrsum)*inv + 1e-4f;
  v4f iv;
  float ctp = 0.f, prp = 1.f;
  #pragma unroll
  for (int k=0;k<4;++k){
    iv[k] = 1.f/(2.f*var[k] + EPSF);
    ctp += bu + __logf(var[k]);
    prp *= var[k];
  }
  // combine the 4 e-quads (lane bits 0-1)
  ctp += __shfl_xor(ctp, 1); ctp += __shfl_xor(ctp, 2);
  prp *= __shfl_xor(prp, 1); prp *= __shfl_xor(prp, 2);

  const size_t mbase = ((size_t)b*NO + o)*ND;
  if (cg == 0){                       // lanes 0..3 each write their e-quad
    *(v4f*)(mean0 + mbase + 4*q) = m;
    *(v4f*)(i2v0  + mbase + 4*q) = iv;
  }
  if (t == 0){
    float cost = ctp * rrsum;
    float x  = 5.0e-4f*(beta_a[o] - cost);   // inv_temp iter0 = 0.01*(1-0.95)
    float aj = 1.f/(1.f + __expf(-x));
    float p1 = sqrtf(6.2831853071795864f*prp + EPSF);
    c0[(size_t)b*NO + o] = aj/(p1 + EPSF);
  }
}

// ---------------- final: reduce e-partials, write output (fp32) -------------
// Same wave-parallel structure as k_mred.
__global__ __launch_bounds__(64) void k_final(
    const float* __restrict__ beta_a, const float* __restrict__ beta_u,
    const float* __restrict__ S1p, const float* __restrict__ S2p,
    const float* __restrict__ Wsp, const int CH,
    float* __restrict__ out)
{
  const int bo = blockIdx.x;
  const int b = bo >> 6, o = bo & 63;
  const int t = threadIdx.x;
  const int q = t & 3, cg = t >> 2;

  v4f s1 = {0.f,0.f,0.f,0.f}, s2 = {0.f,0.f,0.f,0.f};
  for (int c = cg; c < CH; c += 16){
    const size_t base = ((((size_t)b*CH)+c)*NO + o)*ND + 4*q;
    s1 += *(const v4f*)(S1p + base);
    s2 += *(const v4f*)(S2p + base);
  }
  #pragma unroll
  for (int off=4; off<64; off<<=1){
    #pragma unroll
    for (int k=0;k<4;++k){
      s1[k] += __shfl_xor(s1[k], off);
      s2[k] += __shfl_xor(s2[k], off);
    }
  }
  float wv = 0.f;
  for (int c = t; c < CH; c += 64)
    wv += Wsp[(((size_t)b*CH)+c)*NO + o];
  #pragma unroll
  for (int off=1; off<64; off<<=1) wv += __shfl_xor(wv, off);

  const float Wsum = wv;
  const float inv = 1.f/(Wsum + EPSF);
  const float bu = beta_u[o];
  v4f m   = s1*inv;
  v4f var = (s2 - 2.f*m*s1 + m*m*Wsum)*inv + 1e-4f;
  float ctp = 0.f, nrm = 0.f;
  #pragma unroll
  for (int k=0;k<4;++k){
    ctp += bu + __logf(var[k]);
    float me = m[k] + EPSF;
    nrm += me*me;
  }
  ctp += __shfl_xor(ctp, 1); ctp += __shfl_xor(ctp, 2);
  nrm += __shfl_xor(nrm, 1); nrm += __shfl_xor(nrm, 2);

  const float cost = ctp * Wsum;
  const float x  = 9.75e-4f*(beta_a[o] - cost);  // inv_temp iter1 = 0.01*(1-0.95^2)
  const float aj = 1.f/(1.f + __expf(-x));
  const float scale = aj/(sqrtf(nrm) + EPSF);
  if (cg == 0){                       // lanes 0..3 each write their e-quad
    *(v4f*)(out + (size_t)bo*ND + 4*q) = scale*m;
  }
}

// ---------------- host ------------------------------------------------------
extern "C" void kernel_launch(void* const* d_in, const int* in_sizes, int n_in,
                              void* d_out, int out_size, void* d_ws, size_t ws_size,
                              hipStream_t stream)
{
  const float* u      = (const float*)d_in[0];
  const float* W      = (const float*)d_in[1];
  const float* beta_a = (const float*)d_in[2];
  const float* beta_u = (const float*)d_in[3];
  const float* bias   = (const float*)d_in[4];
  float* ws  = (float*)d_ws;
  float* out = (float*)d_out;

  const size_t base_f = 2u*NB*NO*ND + NB*NO;                  // 135,168 floats
  auto need = [&](int ch){
    return (base_f + 2u*(size_t)NB*ch*NO*ND + (size_t)NB*ch*NO)*4;
  };
  const bool big = (ws_size >= need(64));
  const int CH = big ? 64 : 32;

  float* mean0= ws;
  float* i2v0 = mean0 + (size_t)NB*NO*ND;
  float* c0   = i2v0 + (size_t)NB*NO*ND;
  float* S1p  = c0   + (size_t)NB*NO;
  float* S2p  = S1p  + (size_t)NB*CH*NO*ND;
  float* Wsp  = S2p  + (size_t)NB*CH*NO*ND;

  // 256-thr blocks, single 66.5 KB tile -> 2 blocks/CU (8 waves/CU,
  // 2 waves/SIMD @128 VGPR). grid = 8 bgs x CH, all co-resident.
  const int GRID = (NB/8)*CH;
  k_heavy<4,false><<<GRID, 256, 0, stream>>>(u, W, bias,
                                             nullptr, nullptr, nullptr,
                                             S1p, S2p, Wsp, CH);
  k_mred<<<NB*NO, 64, 0, stream>>>(beta_a, beta_u, S1p, S2p, Wsp, CH,
                                   mean0, i2v0, c0);
  k_heavy<4,true><<<GRID, 256, 0, stream>>>(u, W, bias,
                                            mean0, i2v0, c0,
                                            S1p, S2p, Wsp, CH);
  k_final<<<NB*NO, 64, 0, stream>>>(beta_a, beta_u, S1p, S2p, Wsp, CH, out);
}

// Round 8
// 326.513 us; speedup vs baseline: 1.1788x; 1.1788x over previous
//
#include <hip/hip_runtime.h>

#define EPSF 1e-8f

constexpr int NB = 64;   // batch
constexpr int NO = 64;   // out capsules
constexpr int NI = 1152; // in capsules
constexpr int ND = 16;   // pose dims

constexpr int RSTRIDE = 260;            // 256 floats + 4 pad (16B-aligned rows)
constexpr int BUFSZ   = 64 * RSTRIDE;   // one W-tile: 64 o-rows (66,560 B)

typedef float v2f __attribute__((ext_vector_type(2)));
typedef float v4f __attribute__((ext_vector_type(4)));

// Placement law measured R0/R1/R6/R7: effective arch-VGPR pool ~256/SIMD
// (gfx950 512 likely split arch/accum). 2 co-resident blocks need
// waves_per_SIMD x VGPR <= 256: 4-wave blocks -> VGPR <= 128 STRICT
// (144 failed in R7). 8-wave blocks can never get 2/CU (needs 64 VGPR ->
// catastrophic spill, R1). 1024-thr blocks fail to launch (R3/R4).

// fp32 row loader ------------------------------------------------------------
__device__ __forceinline__ void loadrow16f(const float* __restrict__ base,
                                           size_t elem, float* f){
  const float4* p = (const float4*)(base + elem);
  float4 x0=p[0], x1=p[1], x2=p[2], x3=p[3];
  f[0]=x0.x; f[1]=x0.y; f[2]=x0.z; f[3]=x0.w;
  f[4]=x1.x; f[5]=x1.y; f[6]=x1.z; f[7]=x1.w;
  f[8]=x2.x; f[9]=x2.y; f[10]=x2.z; f[11]=x2.w;
  f[12]=x3.x; f[13]=x3.y; f[14]=x3.z; f[15]=x3.w;
}

// async global->LDS, 16 B per lane; lds dst is wave-uniform base + lane*16
__device__ __forceinline__ void gl_lds16(const float* g, float* l){
  __builtin_amdgcn_global_load_lds(
      (const __attribute__((address_space(1))) unsigned int*)g,
      (__attribute__((address_space(3))) unsigned int*)l,
      16, 0, 0);
}

// ---------------- m-pass heavy kernel (slimmed, 2 blocks/CU) ---------------
// NW=4 (256-thr), SINGLE 66,560 B tile -> 2 blocks/CU = 8 waves/CU in two
// independent barrier domains: block A computes while block B drains DMA.
// Register slimming to clear the 128-VGPR placement bound:
//  (1) m-pass wg = av is known BEFORE V -> fuse: V[e] computed then consumed
//      immediately (no V[16] array, -30 regs).
//  (2) bias factored out of V: accumulate RAW Vr = W.u moments; k_mred
//      applies S1 += B*wsum, S2 += 2B*S1raw + B^2*wsum exactly (B=bias+EPS).
//      No bs[16] (-16 regs).
//  (3) stage loop #pragma unroll 1 with incremental pointers (few addr regs).
// Loop = 2 barriers/column: sync(reads done) -> stage -> u-load (overlaps own
// DMA) -> sync(drain) -> fused compute.
__global__ __launch_bounds__(256, 2) void k_mpass(
    const float* __restrict__ u, const float* __restrict__ W,
    float* __restrict__ S1p, float* __restrict__ S2p, float* __restrict__ Wsp,
    const int CH)
{
  const int CI = NI / CH;
  const int bid = blockIdx.x;
  const int bg = bid / CH, c = bid % CH;
  const int t = threadIdx.x, lane = t & 63, w = t >> 6;
  const int b0 = bg*8 + 2*w, b1 = b0 + 1;
  const int i0 = c*CI;

  __shared__ float buf[BUFSZ];   // 66,560 B -> 2 blocks/CU

  v2f S1[16], S2[16]; v2f wsum = {0.f, 0.f};
  #pragma unroll
  for (int e=0;e<16;++e){ S1[e]=v2f{0.f,0.f}; S2[e]=v2f{0.f,0.f}; }

  const float* row = &buf[lane*RSTRIDE];

  for (int ii=0; ii<CI; ++ii){
    const int i = i0 + ii;
    __syncthreads();               // prior column's buf reads complete
    // stage: wave w covers rows w*16..w*16+15, incremental pointers
    {
      const float* g = W + (size_t)i*256 + (size_t)(w*16)*NI*256
                         + (size_t)lane*4;
      float* l = buf + (w*16)*RSTRIDE;
      #pragma unroll 1
      for (int r=0;r<16;++r){
        gl_lds16(g, l);
        g += (size_t)NI*256;
        l += RSTRIDE;
      }
    }

    // u rows for both batches (global, independent of buf -> overlaps DMA)
    v2f u01[16];
    {
      const float4* pa = (const float4*)(u + ((size_t)b0*NI + i)*ND);
      const float4* pb = (const float4*)(u + ((size_t)b1*NI + i)*ND);
      #pragma unroll
      for (int q=0;q<4;++q){
        float4 xa = pa[q], xb = pb[q];
        u01[q*4+0] = v2f{xa.x, xb.x};
        u01[q*4+1] = v2f{xa.y, xb.y};
        u01[q*4+2] = v2f{xa.z, xb.z};
        u01[q*4+3] = v2f{xa.w, xb.w};
      }
    }
    v2f ss = {0.f, 0.f};
    #pragma unroll
    for (int d=0;d<16;++d){ v2f x = u01[d] + EPSF; ss += x*x; }
    const v2f av = {sqrtf(ss.x), sqrtf(ss.y)};

    __syncthreads();               // stage DMA drained

    // fused: V[e] computed and consumed immediately (raw, no bias)
    #pragma unroll
    for (int e=0;e<16;++e){
      v2f Ve = {0.f, 0.f};
      #pragma unroll
      for (int dq=0; dq<4; ++dq){
        const float4 wv = *(const float4*)(row + e*16 + dq*4);
        const int d = dq*4;
        Ve += wv.x*u01[d+0];
        Ve += wv.y*u01[d+1];
        Ve += wv.z*u01[d+2];
        Ve += wv.w*u01[d+3];
      }
      v2f tv = av*Ve;
      S1[e] += tv;
      S2[e] += tv*Ve;
    }
    wsum += av;
  }

  const size_t ba = (((size_t)b0*CH + c)*NO + lane);
  const size_t bb = (((size_t)b1*CH + c)*NO + lane);
  #pragma unroll
  for (int e=0;e<16;++e){
    S1p[ba*ND+e]=S1[e].x; S2p[ba*ND+e]=S2[e].x;
    S1p[bb*ND+e]=S1[e].y; S2p[bb*ND+e]=S2[e].y;
  }
  Wsp[ba] = wsum.x; Wsp[bb] = wsum.y;   // = per-slice sum of a_i
}

// ---------------- e-pass heavy kernel (R0-proven, unchanged) ----------------
// Softmax needs all 16 e before wg -> V can't stream; stays NW=8, dbuf
// 133 KB, (512,2)->128 VGPR, 1 block/CU, measured 131 us.
template<int NW, bool ESTEP>
__global__ __launch_bounds__(NW*64, 2) void k_heavy(
    const float* __restrict__ u, const float* __restrict__ W,
    const float* __restrict__ bias,
    const float* __restrict__ mean0, const float* __restrict__ i2v0,
    const float* __restrict__ c0,
    float* __restrict__ S1p, float* __restrict__ S2p, float* __restrict__ Wsp,
    const int CH)
{
  const int CI = NI / CH;
  constexpr int ROWS = 64 / NW;
  const int bid = blockIdx.x;
  const int bg = bid / CH, c = bid % CH;
  const int t = threadIdx.x, lane = t & 63, w = t >> 6;
  const int b0 = bg*(2*NW) + 2*w, b1 = b0 + 1;
  const int i0 = c*CI;

  __shared__ float buf[2*BUFSZ];   // 133,120 B

  float bs[16]; loadrow16f(bias, (size_t)lane*ND, bs);
  v2f mr[16], ir[16]; v2f c01 = {0.f, 0.f};
  if (ESTEP){
    const size_t m0 = ((size_t)b0*NO + lane)*ND;
    const size_t m1 = ((size_t)b1*NO + lane)*ND;
    #pragma unroll
    for (int e=0;e<16;++e){
      mr[e] = v2f{mean0[m0+e], mean0[m1+e]};
      ir[e] = v2f{i2v0[m0+e], i2v0[m1+e]};
    }
    c01 = v2f{c0[(size_t)b0*NO + lane], c0[(size_t)b1*NO + lane]};
  }

  v2f S1[16], S2[16]; v2f wsum = {0.f, 0.f};
  #pragma unroll
  for (int e=0;e<16;++e){ S1[e]=v2f{0.f,0.f}; S2[e]=v2f{0.f,0.f}; }

  auto stage = [&](int p, int i){
    const float* gbase = W + (size_t)i*256 + (size_t)lane*4;
    float* lbase = &buf[p*BUFSZ];
    #pragma unroll
    for (int r=0;r<ROWS;++r){
      const int o = w*ROWS + r;
      gl_lds16(gbase + (size_t)o*NI*256, lbase + o*RSTRIDE);
    }
  };

  int p = 0;
  stage(0, i0);

  for (int ii=0; ii<CI; ++ii){
    __syncthreads();
    if (ii+1 < CI) stage(p^1, i0+ii+1);

    const int i = i0 + ii;
    v2f u01[16];
    {
      const float4* pa = (const float4*)(u + ((size_t)b0*NI + i)*ND);
      const float4* pb = (const float4*)(u + ((size_t)b1*NI + i)*ND);
      #pragma unroll
      for (int q=0;q<4;++q){
        float4 xa = pa[q], xb = pb[q];
        u01[q*4+0] = v2f{xa.x, xb.x};
        u01[q*4+1] = v2f{xa.y, xb.y};
        u01[q*4+2] = v2f{xa.z, xb.z};
        u01[q*4+3] = v2f{xa.w, xb.w};
      }
    }
    v2f ss = {0.f, 0.f};
    #pragma unroll
    for (int d=0;d<16;++d){ v2f x = u01[d] + EPSF; ss += x*x; }
    const v2f av = {sqrtf(ss.x), sqrtf(ss.y)};

    v2f V[16];
    #pragma unroll
    for (int e=0;e<16;++e){ float b = bs[e] + EPSF; V[e] = v2f{b, b}; }
    const float* row = &buf[p*BUFSZ + lane*RSTRIDE];
    #pragma unroll
    for (int e=0;e<16;++e){
      #pragma unroll
      for (int dq=0; dq<4; ++dq){
        const float4 wv = *(const float4*)(row + e*16 + dq*4);
        const int d = dq*4;
        V[e] += wv.x*u01[d+0];
        V[e] += wv.y*u01[d+1];
        V[e] += wv.z*u01[d+2];
        V[e] += wv.w*u01[d+3];
      }
    }

    v2f wg;
    if (ESTEP){
      v2f la = {0.f, 0.f};
      #pragma unroll
      for (int e=0;e<16;++e){ v2f df = V[e]-mr[e]; la += df*df*ir[e]; }
      v2f ap = c01 * v2f{__expf(-la.x), __expf(-la.y)};
      float q0 = ap.x, q1 = ap.y;
      #pragma unroll
      for (int off=32; off; off>>=1){
        q0 += __shfl_xor(q0, off);
        q1 += __shfl_xor(q1, off);
      }
      wg = v2f{ap.x/(q0 + EPSF)*av.x, ap.y/(q1 + EPSF)*av.y};
    } else {
      wg = av;
    }
    wsum += wg;
    #pragma unroll
    for (int e=0;e<16;++e){
      v2f tv = wg*V[e]; S1[e]+=tv; S2[e]+=tv*V[e];
    }
    p ^= 1;
  }

  const size_t ba = (((size_t)b0*CH + c)*NO + lane);
  const size_t bb = (((size_t)b1*CH + c)*NO + lane);
  #pragma unroll
  for (int e=0;e<16;++e){
    S1p[ba*ND+e]=S1[e].x; S2p[ba*ND+e]=S2[e].x;
    S1p[bb*ND+e]=S1[e].y; S2p[bb*ND+e]=S2[e].y;
  }
  Wsp[ba] = wsum.x; Wsp[bb] = wsum.y;
}

// ---------------- reduce m-step partials -> mean0,i2v0,c0 -------------------
// Wave-parallel (R5) + exact bias restoration for the raw m-pass partials:
// B = bias+EPS;  S2 += 2B*S1raw + B^2*wv;  S1 += B*wv  (then scale by 1/64).
__global__ __launch_bounds__(64) void k_mred(
    const float* __restrict__ beta_a, const float* __restrict__ beta_u,
    const float* __restrict__ bias,
    const float* __restrict__ S1p, const float* __restrict__ S2p,
    const float* __restrict__ Wsp, const int CH,
    float* __restrict__ mean0, float* __restrict__ i2v0, float* __restrict__ c0)
{
  const int bo = blockIdx.x;
  const int b = bo >> 6, o = bo & 63;
  const int t = threadIdx.x;
  const int q = t & 3, cg = t >> 2;

  v4f s1 = {0.f,0.f,0.f,0.f}, s2 = {0.f,0.f,0.f,0.f};
  for (int c = cg; c < CH; c += 16){
    const size_t base = ((((size_t)b*CH)+c)*NO + o)*ND + 4*q;
    s1 += *(const v4f*)(S1p + base);
    s2 += *(const v4f*)(S2p + base);
  }
  #pragma unroll
  for (int off=4; off<64; off<<=1){
    #pragma unroll
    for (int k=0;k<4;++k){
      s1[k] += __shfl_xor(s1[k], off);
      s2[k] += __shfl_xor(s2[k], off);
    }
  }
  float wv = 0.f;
  for (int c = t; c < CH; c += 64)
    wv += Wsp[(((size_t)b*CH)+c)*NO + o];
  #pragma unroll
  for (int off=1; off<64; off<<=1) wv += __shfl_xor(wv, off);

  // bias restoration (exact algebra; order matters: s2 uses raw s1)
  {
    v4f Bq = *(const v4f*)(bias + (size_t)o*ND + 4*q);
    Bq += EPSF;
    s2 += 2.f*Bq*s1 + Bq*Bq*wv;
    s1 += Bq*wv;
  }

  const float rrsum = wv * (1.f/64.f);
  const float inv = 1.f/(rrsum + EPSF);
  const float bu = beta_u[o];
  v4f T1 = s1*(1.f/64.f), T2 = s2*(1.f/64.f);
  v4f m   = T1*inv;
  v4f var = (T2 - 2.f*m*T1 + m*m*rrsum)*inv + 1e-4f;
  v4f iv;
  float ctp = 0.f, prp = 1.f;
  #pragma unroll
  for (int k=0;k<4;++k){
    iv[k] = 1.f/(2.f*var[k] + EPSF);
    ctp += bu + __logf(var[k]);
    prp *= var[k];
  }
  ctp += __shfl_xor(ctp, 1); ctp += __shfl_xor(ctp, 2);
  prp *= __shfl_xor(prp, 1); prp *= __shfl_xor(prp, 2);

  const size_t mbase = ((size_t)b*NO + o)*ND;
  if (cg == 0){
    *(v4f*)(mean0 + mbase + 4*q) = m;
    *(v4f*)(i2v0  + mbase + 4*q) = iv;
  }
  if (t == 0){
    float cost = ctp * rrsum;
    float x  = 5.0e-4f*(beta_a[o] - cost);   // inv_temp iter0 = 0.01*(1-0.95)
    float aj = 1.f/(1.f + __expf(-x));
    float p1 = sqrtf(6.2831853071795864f*prp + EPSF);
    c0[(size_t)b*NO + o] = aj/(p1 + EPSF);
  }
}

// ---------------- final: reduce e-partials (bias-inclusive), write out ------
__global__ __launch_bounds__(64) void k_final(
    const float* __restrict__ beta_a, const float* __restrict__ beta_u,
    const float* __restrict__ S1p, const float* __restrict__ S2p,
    const float* __restrict__ Wsp, const int CH,
    float* __restrict__ out)
{
  const int bo = blockIdx.x;
  const int b = bo >> 6, o = bo & 63;
  const int t = threadIdx.x;
  const int q = t & 3, cg = t >> 2;

  v4f s1 = {0.f,0.f,0.f,0.f}, s2 = {0.f,0.f,0.f,0.f};
  for (int c = cg; c < CH; c += 16){
    const size_t base = ((((size_t)b*CH)+c)*NO + o)*ND + 4*q;
    s1 += *(const v4f*)(S1p + base);
    s2 += *(const v4f*)(S2p + base);
  }
  #pragma unroll
  for (int off=4; off<64; off<<=1){
    #pragma unroll
    for (int k=0;k<4;++k){
      s1[k] += __shfl_xor(s1[k], off);
      s2[k] += __shfl_xor(s2[k], off);
    }
  }
  float wv = 0.f;
  for (int c = t; c < CH; c += 64)
    wv += Wsp[(((size_t)b*CH)+c)*NO + o];
  #pragma unroll
  for (int off=1; off<64; off<<=1) wv += __shfl_xor(wv, off);

  const float Wsum = wv;
  const float inv = 1.f/(Wsum + EPSF);
  const float bu = beta_u[o];
  v4f m   = s1*inv;
  v4f var = (s2 - 2.f*m*s1 + m*m*Wsum)*inv + 1e-4f;
  float ctp = 0.f, nrm = 0.f;
  #pragma unroll
  for (int k=0;k<4;++k){
    ctp += bu + __logf(var[k]);
    float me = m[k] + EPSF;
    nrm += me*me;
  }
  ctp += __shfl_xor(ctp, 1); ctp += __shfl_xor(ctp, 2);
  nrm += __shfl_xor(nrm, 1); nrm += __shfl_xor(nrm, 2);

  const float cost = ctp * Wsum;
  const float x  = 9.75e-4f*(beta_a[o] - cost);  // inv_temp iter1 = 0.01*(1-0.95^2)
  const float aj = 1.f/(1.f + __expf(-x));
  const float scale = aj/(sqrtf(nrm) + EPSF);
  if (cg == 0){
    *(v4f*)(out + (size_t)bo*ND + 4*q) = scale*m;
  }
}

// ---------------- host ------------------------------------------------------
extern "C" void kernel_launch(void* const* d_in, const int* in_sizes, int n_in,
                              void* d_out, int out_size, void* d_ws, size_t ws_size,
                              hipStream_t stream)
{
  const float* u      = (const float*)d_in[0];
  const float* W      = (const float*)d_in[1];
  const float* beta_a = (const float*)d_in[2];
  const float* beta_u = (const float*)d_in[3];
  const float* bias   = (const float*)d_in[4];
  float* ws  = (float*)d_ws;
  float* out = (float*)d_out;

  const size_t base_f = 2u*NB*NO*ND + NB*NO;                  // 135,168 floats
  auto need = [&](int ch){
    return (base_f + 2u*(size_t)NB*ch*NO*ND + (size_t)NB*ch*NO)*4;
  };
  const bool big = (ws_size >= need(64));
  const int CH = big ? 64 : 32;

  float* mean0= ws;
  float* i2v0 = mean0 + (size_t)NB*NO*ND;
  float* c0   = i2v0 + (size_t)NB*NO*ND;
  float* S1p  = c0   + (size_t)NB*NO;
  float* S2p  = S1p  + (size_t)NB*CH*NO*ND;
  float* Wsp  = S2p  + (size_t)NB*CH*NO*ND;

  // m-pass: slim NW=4 single-buffer kernel, 512 blocks -> 2 blocks/CU
  k_mpass<<<(NB/8)*CH, 256, 0, stream>>>(u, W, S1p, S2p, Wsp, CH);
  k_mred<<<NB*NO, 64, 0, stream>>>(beta_a, beta_u, bias, S1p, S2p, Wsp, CH,
                                   mean0, i2v0, c0);
  if (big){
    // e-pass: R0-proven NW=8 dbuf kernel
    k_heavy<8,true><<<(NB/16)*CH, 512, 0, stream>>>(u, W, bias,
                                                    mean0, i2v0, c0,
                                                    S1p, S2p, Wsp, CH);
  } else {
    k_heavy<4,true><<<(NB/8)*CH, 256, 0, stream>>>(u, W, bias,
                                                   mean0, i2v0, c0,
                                                   S1p, S2p, Wsp, CH);
  }
  k_final<<<NB*NO, 64, 0, stream>>>(beta_a, beta_u, S1p, S2p, Wsp, CH, out);
}